// Round 6
// baseline (465.062 us; speedup 1.0000x reference)
//
#include <hip/hip_runtime.h>
#include <math.h>

#define BB 9
#define NN 4096
#define DD 2048
#define NPAIR 45   // pairs i<=j (includes diagonal = squared norms)
#define NOFF 36    // pairs i<j
#define WSCOL 64   // scatter columns to avoid atomic same-address contention
#define CHUNK 1024 // floats of d per LDS tile (2 chunks cover D=2048)

// ws layout: float part[NOFF][WSCOL]  (36*64 = 2304 floats)

typedef const __attribute__((address_space(1))) void* as1_t;
typedef __attribute__((address_space(3))) void* as3_t;

__global__ void zero_ws_kernel(float* __restrict__ ws) {
    int t = blockIdx.x * blockDim.x + threadIdx.x;
    if (t < NOFF * WSCOL) ws[t] = 0.0f;
}

// One block per n. Per 1024-float chunk of d, each wave issues 9 async
// global_load_lds (16B/lane, VGPR-free in flight -> 9KB/wave outstanding;
// R3-R5 proved VGPR-destination loads get serialized/spilled by the
// allocator). Wave w stages columns [256w,256w+256) of all 9 rows; thread
// tid=64w+l consumes exactly that quarter via ds_read_b128 -> wave-private
// producer/consumer; barriers only guard the single-buffer overwrite.
__global__ __launch_bounds__(256, 4) void pairdot_kernel(const float* __restrict__ x,
                                                         float* __restrict__ ws) {
    const int tid = threadIdx.x;
    const int wave = tid >> 6;
    const int lane = tid & 63;
    const int n = blockIdx.x;   // n in [0, 4096)

    __shared__ float smem[BB][CHUNK];   // 36 KB
    __shared__ float psum[4][NPAIR];
    __shared__ float dotv[NPAIR];

    const size_t rowstride = (size_t)NN * DD;

    float acc[NPAIR];
#pragma unroll
    for (int p = 0; p < NPAIR; ++p) acc[p] = 0.0f;

#pragma unroll 1
    for (int c = 0; c < DD / CHUNK; ++c) {
        if (c) __syncthreads();   // previous chunk fully consumed before overwrite
        const float* g0 = x + (size_t)n * DD + c * CHUNK + wave * 256 + lane * 4;
#pragma unroll
        for (int i = 0; i < BB; ++i) {
            __builtin_amdgcn_global_load_lds((as1_t)(g0 + (size_t)i * rowstride),
                                             (as3_t)&smem[i][wave * 256],
                                             16, 0, 0);
        }
        __syncthreads();   // compiler emits s_waitcnt vmcnt(0) before s_barrier -> data landed

        float4 v[BB];
#pragma unroll
        for (int i = 0; i < BB; ++i) v[i] = *(const float4*)&smem[i][tid * 4];
        int p = 0;
#pragma unroll
        for (int i = 0; i < BB; ++i) {
#pragma unroll
            for (int j = i; j < BB; ++j) {
                acc[p] += v[i].x * v[j].x + v[i].y * v[j].y
                        + v[i].z * v[j].z + v[i].w * v[j].w;
                ++p;
            }
        }
    }

    // Butterfly reduction across 64 lanes of each wave.
#pragma unroll
    for (int p = 0; p < NPAIR; ++p) {
        float a = acc[p];
#pragma unroll
        for (int m = 32; m >= 1; m >>= 1) a += __shfl_xor(a, m, 64);
        acc[p] = a;
    }
    if (lane < NPAIR) psum[wave][lane] = acc[lane];  // lane p holds... all lanes hold full sum; store acc[p] per p
    // NOTE: every lane holds every acc fully reduced; have lanes 0..44 each store one
    if (lane == 0) {
#pragma unroll
        for (int p = 0; p < NPAIR; ++p) psum[wave][p] = acc[p];
    }
    __syncthreads();

    if (tid < NPAIR) {
        dotv[tid] = psum[0][tid] + psum[1][tid] + psum[2][tid] + psum[3][tid];
    }
    __syncthreads();

    if (tid < NOFF) {
        // map off-diagonal index tid -> (i,j), i<j  (row-major, matches finalize)
        int q = tid, i = 0;
        while (q >= BB - 1 - i) { q -= BB - 1 - i; ++i; }
        const int j = i + 1 + q;
        const int pii = i * BB - i * (i - 1) / 2;          // packed (i,i)
        const int pjj = j * BB - j * (j - 1) / 2;          // packed (j,j)
        const int pij = pii + (j - i);                     // packed (i,j)
        float sq = fmaxf(dotv[pii] + dotv[pjj] - 2.0f * dotv[pij], 0.0f);
        atomicAdd(&ws[tid * WSCOL + (n & (WSCOL - 1))], __expf(-10.0f * sq));
    }
}

// Parallel finalize: 4 waves x 9 pairs, one coalesced load + butterfly each;
// then assemble 9x9 in LDS (fp64) and lane-parallel LU w/ partial pivoting.
__global__ __launch_bounds__(256, 1) void finalize_kernel(const float* __restrict__ ws,
                                                          float* __restrict__ out) {
    const int tid = threadIdx.x;
    const int wave = tid >> 6;
    const int lane = tid & 63;

    __shared__ float snm_f[NOFF];
#pragma unroll 1
    for (int t = 0; t < 9; ++t) {
        const int q = wave * 9 + t;
        float s = ws[q * WSCOL + lane];
#pragma unroll
        for (int m = 32; m >= 1; m >>= 1) s += __shfl_xor(s, m, 64);
        if (lane == 0) snm_f[q] = s;
    }
    __syncthreads();

    __shared__ double A[BB * BB];
    __shared__ double Fs[BB];
    __shared__ int piv_s;

    const double inv_n = 1.0 / (double)NN;
    if (tid < BB * BB) {
        const int r = tid / BB, c = tid % BB;
        if (r == c) {
            A[tid] = 0.0;
        } else {
            const int i = r < c ? r : c;
            const int j = r < c ? c : r;
            const int q = i * (2 * BB - 1 - i) / 2 + (j - i - 1);
            A[tid] = (double)snm_f[q] * inv_n;
        }
    }
    __syncthreads();

    double direct = 0.0, detv = 1.0;
    if (tid == 0) {
        for (int q = 0; q < NOFF; ++q) direct += (double)snm_f[q];
        direct = 2.0 * direct * inv_n;
    }

    for (int k = 0; k < BB; ++k) {
        if (tid == 0) {
            int piv = k;
            double mx = fabs(A[k * BB + k]);
            for (int r = k + 1; r < BB; ++r) {
                double a = fabs(A[r * BB + k]);
                if (a > mx) { mx = a; piv = r; }
            }
            piv_s = piv;
        }
        __syncthreads();
        const int piv = piv_s;
        double tk = 0.0, tp = 0.0;
        if (tid < BB) { tk = A[k * BB + tid]; tp = A[piv * BB + tid]; }
        __syncthreads();
        if (tid < BB) { A[k * BB + tid] = tp; A[piv * BB + tid] = tk; }
        __syncthreads();
        if (tid == 0) {
            detv *= A[k * BB + k];
            if (piv != k) detv = -detv;
        }
        if (tid > k && tid < BB) Fs[tid] = A[tid * BB + k] / A[k * BB + k];
        __syncthreads();
        if (tid < BB * BB) {
            const int r = tid / BB, c = tid % BB;
            if (r > k && c >= k) A[tid] -= Fs[r] * A[k * BB + c];
        }
        __syncthreads();
    }

    if (tid == 0) {
        out[0] = (float)direct;                     // direct_div
        out[1] = (float)(-detv);                    // det_div
        out[2] = (detv > 0.0) ? (float)(-log(detv))
                              : __builtin_nanf(""); // logdet_div
    }
}

extern "C" void kernel_launch(void* const* d_in, const int* in_sizes, int n_in,
                              void* d_out, int out_size, void* d_ws, size_t ws_size,
                              hipStream_t stream) {
    const float* x = (const float*)d_in[0];
    float* out = (float*)d_out;
    float* ws = (float*)d_ws;   // NOFF*WSCOL*4 = 9216 bytes

    zero_ws_kernel<<<(NOFF * WSCOL + 255) / 256, 256, 0, stream>>>(ws);
    pairdot_kernel<<<NN, 256, 0, stream>>>(x, ws);
    finalize_kernel<<<1, 256, 0, stream>>>(ws, out);
}